// Round 1
// baseline (729.379 us; speedup 1.0000x reference)
//
#include <hip/hip_runtime.h>
#include <hip/hip_bf16.h>
#include <cstdint>

typedef __attribute__((ext_vector_type(4))) float f32x4;
typedef __attribute__((ext_vector_type(8))) short s16x8;

#define MAXDEG 256

__device__ inline unsigned short f2bf(float f) {
    unsigned u = __float_as_uint(f);
    u = (u + 0x7fffu + ((u >> 16) & 1u)) >> 16;   // round-to-nearest-even
    return (unsigned short)u;
}
__device__ inline float bf_lo(unsigned x) { return __uint_as_float(x << 16); }
__device__ inline float bf_hi(unsigned x) { return __uint_as_float(x & 0xffff0000u); }

// ---------------- W (f32) -> bf16 ----------------
__global__ void convW(const float* __restrict__ W, unsigned short* __restrict__ Wb) {
    int i = blockIdx.x * 256 + threadIdx.x;
    if (i < 256 * 256) Wb[i] = f2bf(W[i]);
}

// ---------------- X (f32) -> bf16, 8 elems/thread ----------------
__global__ __launch_bounds__(256) void convX(const float* __restrict__ X,
                                             unsigned short* __restrict__ Xb) {
    size_t i = ((size_t)blockIdx.x * 256 + threadIdx.x) * 8;
    f32x4 x0 = *(const f32x4*)(X + i);
    f32x4 x1 = *(const f32x4*)(X + i + 4);
    s16x8 r;
    r[0] = (short)f2bf(x0.x); r[1] = (short)f2bf(x0.y);
    r[2] = (short)f2bf(x0.z); r[3] = (short)f2bf(x0.w);
    r[4] = (short)f2bf(x1.x); r[5] = (short)f2bf(x1.y);
    r[6] = (short)f2bf(x1.z); r[7] = (short)f2bf(x1.w);
    *(s16x8*)(Xb + i) = r;
}

// ---------------- h = X @ W^T + b, stored bf16 (bf16 inputs) ----------------
// block = 256 threads = 4 waves. Block tile: 32 nodes x 256 outs.
// Wave w covers outs [w*64, w*64+64); 2 m-tiles of 16 nodes.
__global__ __launch_bounds__(256) void gemm_h(
    const unsigned short* __restrict__ Xb, const unsigned short* __restrict__ Wb,
    const float* __restrict__ bvec, unsigned short* __restrict__ Hb) {
    const int lane = threadIdx.x & 63;
    const int wave = threadIdx.x >> 6;
    const int l15 = lane & 15, quad = lane >> 4;
    const int nbase = blockIdx.x * 32;
    const int obase = wave * 64;

    f32x4 acc[2][4] = {};
#pragma unroll
    for (int k = 0; k < 256; k += 32) {
        s16x8 afr[2];
#pragma unroll
        for (int mt = 0; mt < 2; ++mt)
            afr[mt] = *(const s16x8*)(Xb + (size_t)(nbase + mt * 16 + l15) * 256 + k + quad * 8);
#pragma unroll
        for (int t = 0; t < 4; ++t) {
            s16x8 bfr = *(const s16x8*)(Wb + (size_t)(obase + t * 16 + l15) * 256 + k + quad * 8);
            acc[0][t] = __builtin_amdgcn_mfma_f32_16x16x32_bf16(afr[0], bfr, acc[0][t], 0, 0, 0);
            acc[1][t] = __builtin_amdgcn_mfma_f32_16x16x32_bf16(afr[1], bfr, acc[1][t], 0, 0, 0);
        }
    }
#pragma unroll
    for (int t = 0; t < 4; ++t) {
        int o = obase + t * 16 + l15;
        float bv = bvec[o];
#pragma unroll
        for (int mt = 0; mt < 2; ++mt) {
#pragma unroll
            for (int r = 0; r < 4; ++r) {
                int node = nbase + mt * 16 + quad * 4 + r;
                Hb[(size_t)node * 256 + o] = f2bf(acc[mt][t][r] + bv);
            }
        }
    }
}

// ---------------- a1/a2 per-node scalar scores ----------------
__global__ __launch_bounds__(256) void a_scores(
    const unsigned short* __restrict__ Hb,
    const float* __restrict__ wa1, const float* __restrict__ ba1,
    const float* __restrict__ wa2, const float* __restrict__ ba2,
    float* __restrict__ a1, float* __restrict__ a2) {
    const int lane = threadIdx.x & 63;
    const int wave = threadIdx.x >> 6;
    const int node = blockIdx.x * 4 + wave;
    uint2 hv = *(const uint2*)(Hb + (size_t)node * 256 + lane * 4);
    float x0 = bf_lo(hv.x), x1 = bf_hi(hv.x), x2 = bf_lo(hv.y), x3 = bf_hi(hv.y);
    f32x4 w1 = *(const f32x4*)(wa1 + lane * 4);
    f32x4 w2 = *(const f32x4*)(wa2 + lane * 4);
    float s1 = x0 * w1.x + x1 * w1.y + x2 * w1.z + x3 * w1.w;
    float s2 = x0 * w2.x + x1 * w2.y + x2 * w2.z + x3 * w2.w;
#pragma unroll
    for (int o = 32; o; o >>= 1) {
        s1 += __shfl_xor(s1, o);
        s2 += __shfl_xor(s2, o);
    }
    if (lane == 0) {
        a1[node] = s1 + ba1[0];
        a2[node] = s2 + ba2[0];
    }
}

// ---------------- CSR build ----------------
// hist with fused rank capture: rank[i] = this edge's ordinal within its row
__global__ void hist_k(const int* __restrict__ rows, int* __restrict__ cnt,
                       int* __restrict__ rank, int e) {
    int i = blockIdx.x * 256 + threadIdx.x;
    if (i < e) rank[i] = atomicAdd(&cnt[rows[i]], 1);
}

__global__ __launch_bounds__(256) void scan1(
    const int* __restrict__ cnt, int* __restrict__ off, int* __restrict__ bsum, int n) {
    __shared__ int lds[256];
    const int tid = threadIdx.x;
    const int base = blockIdx.x * 2048 + tid * 8;
    int v[8];
    int run = 0;
#pragma unroll
    for (int j = 0; j < 8; ++j) {
        int idx = base + j;
        int x = (idx < n) ? cnt[idx] : 0;
        run += x;
        v[j] = run;
    }
    lds[tid] = run;
    __syncthreads();
#pragma unroll
    for (int ofs = 1; ofs < 256; ofs <<= 1) {
        int t = (tid >= ofs) ? lds[tid - ofs] : 0;
        __syncthreads();
        lds[tid] += t;
        __syncthreads();
    }
    int pre = lds[tid] - run;
#pragma unroll
    for (int j = 0; j < 8; ++j) {
        int idx = base + j;
        if (idx < n) off[1 + idx] = v[j] + pre;
    }
    if (tid == 255) bsum[blockIdx.x] = lds[255];
}

// wave-parallel exclusive scan of block sums (was: serial 1-thread loop,
// ~nb dependent global round-trips on the CSR critical path)
__global__ void scan2(int* __restrict__ bsum, int* __restrict__ off, int nb) {
    const int lane = threadIdx.x & 63;
    int run = 0;
    for (int base = 0; base < nb; base += 64) {
        int i = base + lane;
        int v = (i < nb) ? bsum[i] : 0;
        int s = v;
#pragma unroll
        for (int o = 1; o < 64; o <<= 1) {
            int t = __shfl_up(s, o);
            if (lane >= o) s += t;
        }
        if (i < nb) bsum[i] = s - v + run;   // exclusive + carry
        run += __shfl(s, 63);                 // chunk total
    }
    if (lane == 0) off[0] = 0;
}

__global__ __launch_bounds__(256) void scan3(
    const int* __restrict__ bsum, int* __restrict__ off, int n) {
    int add = bsum[blockIdx.x];
    int base = blockIdx.x * 2048 + threadIdx.x * 8;
#pragma unroll
    for (int j = 0; j < 8; ++j) {
        int idx = base + j;
        if (idx < n) off[1 + idx] += add;
    }
}

__global__ void scatter_k(const int* __restrict__ rows, const int* __restrict__ colsIn,
                          const int* __restrict__ rank, const int* __restrict__ off,
                          int* __restrict__ colsOut, int e) {
    int i = blockIdx.x * 256 + threadIdx.x;
    if (i < e) {
        int p = off[rows[i]] + rank[i];
        colsOut[p] = colsIn[i];
    }
}

// ---------------- softmax + weighted aggregation ----------------
// block = 256 = 4 waves, one node per wave. Lane covers 4 of 256 dims.
// Unrolled x4 with independent accumulators; 1/s folded into final scale.
__global__ __launch_bounds__(256) void aggregate(
    const int* __restrict__ off, const int* __restrict__ cols,
    const float* __restrict__ a1, const float* __restrict__ a2,
    const unsigned short* __restrict__ Hb, float* __restrict__ out) {
    __shared__ float s_ev[4][MAXDEG];
    __shared__ int s_col[4][MAXDEG];
    const int lane = threadIdx.x & 63;
    const int wave = threadIdx.x >> 6;
    const int node = blockIdx.x * 4 + wave;
    const int o0 = off[node];
    const int deg = off[node + 1] - o0;
    const float a1n = a1[node];

    // pass 1: scores -> exp (unnormalized), LDS stash, denominator
    float s = 0.0f;
    for (int i = lane; i < deg; i += 64) {
        int c = cols[o0 + i];
        float v = a1n + a2[c];
        v = (v > 0.0f) ? v : 0.01f * v;
        float ev = __expf(v);
        if (i < MAXDEG) {
            s_ev[wave][i] = ev;
            s_col[wave][i] = c;
        }
        s += ev;
    }
#pragma unroll
    for (int o = 32; o; o >>= 1) s += __shfl_xor(s, o);
    float inv = (s > 0.0f) ? 1.0f / s : 0.0f;
    __syncthreads();

    // pass 2: out[node] = (sum ev * h[col]) * inv
    f32x4 acc0 = {0,0,0,0}, acc1 = {0,0,0,0}, acc2 = {0,0,0,0}, acc3 = {0,0,0,0};
    const int cbase = lane * 4;
    const int nfast = (deg < MAXDEG) ? deg : MAXDEG;
    const int nf4 = nfast & ~3;
    int i = 0;
    for (; i < nf4; i += 4) {
        float w0 = s_ev[wave][i],     w1 = s_ev[wave][i + 1];
        float w2 = s_ev[wave][i + 2], w3 = s_ev[wave][i + 3];
        int c0 = s_col[wave][i],     c1 = s_col[wave][i + 1];
        int c2 = s_col[wave][i + 2], c3 = s_col[wave][i + 3];
        uint2 h0 = *(const uint2*)(Hb + (size_t)c0 * 256 + cbase);
        uint2 h1 = *(const uint2*)(Hb + (size_t)c1 * 256 + cbase);
        uint2 h2 = *(const uint2*)(Hb + (size_t)c2 * 256 + cbase);
        uint2 h3 = *(const uint2*)(Hb + (size_t)c3 * 256 + cbase);
        acc0.x += w0 * bf_lo(h0.x); acc0.y += w0 * bf_hi(h0.x);
        acc0.z += w0 * bf_lo(h0.y); acc0.w += w0 * bf_hi(h0.y);
        acc1.x += w1 * bf_lo(h1.x); acc1.y += w1 * bf_hi(h1.x);
        acc1.z += w1 * bf_lo(h1.y); acc1.w += w1 * bf_hi(h1.y);
        acc2.x += w2 * bf_lo(h2.x); acc2.y += w2 * bf_hi(h2.x);
        acc2.z += w2 * bf_lo(h2.y); acc2.w += w2 * bf_hi(h2.y);
        acc3.x += w3 * bf_lo(h3.x); acc3.y += w3 * bf_hi(h3.x);
        acc3.z += w3 * bf_lo(h3.y); acc3.w += w3 * bf_hi(h3.y);
    }
    for (; i < nfast; ++i) {
        float w = s_ev[wave][i];
        int c = s_col[wave][i];
        uint2 hv = *(const uint2*)(Hb + (size_t)c * 256 + cbase);
        acc0.x += w * bf_lo(hv.x); acc0.y += w * bf_hi(hv.x);
        acc0.z += w * bf_lo(hv.y); acc0.w += w * bf_hi(hv.y);
    }
    for (int j = MAXDEG; j < deg; ++j) {  // rare overflow path
        int c = cols[o0 + j];
        float v = a1n + a2[c];
        v = (v > 0.0f) ? v : 0.01f * v;
        float w = __expf(v);
        uint2 hv = *(const uint2*)(Hb + (size_t)c * 256 + cbase);
        acc0.x += w * bf_lo(hv.x); acc0.y += w * bf_hi(hv.x);
        acc0.z += w * bf_lo(hv.y); acc0.w += w * bf_hi(hv.y);
    }
    f32x4 acc;
    acc.x = ((acc0.x + acc1.x) + (acc2.x + acc3.x)) * inv;
    acc.y = ((acc0.y + acc1.y) + (acc2.y + acc3.y)) * inv;
    acc.z = ((acc0.z + acc1.z) + (acc2.z + acc3.z)) * inv;
    acc.w = ((acc0.w + acc1.w) + (acc2.w + acc3.w)) * inv;
    *(f32x4*)(out + (size_t)node * 256 + cbase) = acc;
}

extern "C" void kernel_launch(void* const* d_in, const int* in_sizes, int n_in,
                              void* d_out, int out_size, void* d_ws, size_t ws_size,
                              hipStream_t stream) {
    const float* X   = (const float*)d_in[0];
    const int*   idx = (const int*)d_in[1];
    const float* W   = (const float*)d_in[2];
    const float* b   = (const float*)d_in[3];
    const float* wa1 = (const float*)d_in[4];
    const float* ba1 = (const float*)d_in[5];
    const float* wa2 = (const float*)d_in[6];
    const float* ba2 = (const float*)d_in[7];
    float* out = (float*)d_out;

    const int n = in_sizes[0] / 256;  // 100000
    const int e = in_sizes[1] / 2;    // 3200000

    char* p = (char*)d_ws;
    auto alloc = [&](size_t bytes) -> char* {
        char* r = p;
        p += (bytes + 255) & ~(size_t)255;
        return r;
    };
    unsigned short* Hb = (unsigned short*)alloc((size_t)n * 256 * 2);
    unsigned short* Xb = (unsigned short*)alloc((size_t)n * 256 * 2);
    unsigned short* Wb = (unsigned short*)alloc(256 * 256 * 2);
    float* a1  = (float*)alloc((size_t)n * 4);
    float* a2  = (float*)alloc((size_t)n * 4);
    int* cnt   = (int*)alloc((size_t)n * 4);
    int* off   = (int*)alloc((size_t)(n + 1) * 4);
    int* bsum  = (int*)alloc(256 * 4);
    int* rank  = (int*)alloc((size_t)e * 4);
    int* colS  = (int*)alloc((size_t)e * 4);

    const int* rows   = idx;
    const int* colsIn = idx + e;

    hipMemsetAsync(cnt, 0, (size_t)n * 4, stream);

    convW<<<256, 256, 0, stream>>>(W, Wb);
    convX<<<(n * 256) / (256 * 8), 256, 0, stream>>>(X, Xb);
    gemm_h<<<n / 32, 256, 0, stream>>>(Xb, Wb, b, Hb);
    a_scores<<<n / 4, 256, 0, stream>>>(Hb, wa1, ba1, wa2, ba2, a1, a2);
    hist_k<<<(e + 255) / 256, 256, 0, stream>>>(rows, cnt, rank, e);
    int nb = (n + 2047) / 2048;
    scan1<<<nb, 256, 0, stream>>>(cnt, off, bsum, n);
    scan2<<<1, 64, 0, stream>>>(bsum, off, nb);
    scan3<<<nb, 256, 0, stream>>>(bsum, off, n);
    scatter_k<<<(e + 255) / 256, 256, 0, stream>>>(rows, colsIn, rank, off, colS, e);
    aggregate<<<n / 4, 256, 0, stream>>>(off, colS, a1, a2, Hb, out);
}

// Round 2
// 708.195 us; speedup vs baseline: 1.0299x; 1.0299x over previous
//
#include <hip/hip_runtime.h>
#include <hip/hip_bf16.h>
#include <cstdint>

typedef __attribute__((ext_vector_type(4))) float f32x4;
typedef __attribute__((ext_vector_type(8))) short s16x8;

#define MAXDEG 256

__device__ inline unsigned short f2bf(float f) {
    unsigned u = __float_as_uint(f);
    u = (u + 0x7fffu + ((u >> 16) & 1u)) >> 16;   // round-to-nearest-even
    return (unsigned short)u;
}
__device__ inline float bf_lo(unsigned x) { return __uint_as_float(x << 16); }
__device__ inline float bf_hi(unsigned x) { return __uint_as_float(x & 0xffff0000u); }

// ================= K1: convX | hist | convW (independent leaves, fused) ==========
__global__ __launch_bounds__(256) void k1_prep(
    const float* __restrict__ X, unsigned short* __restrict__ Xb,
    const float* __restrict__ W, unsigned short* __restrict__ Wb,
    const int* __restrict__ rows, int* __restrict__ cnt, int* __restrict__ rank,
    int nconvx, int nhist, int e) {
    const int tid = threadIdx.x;
    const int b = blockIdx.x;
    if (b < nconvx) {
        // X f32 -> bf16, 8 elems/thread
        size_t i = ((size_t)b * 256 + tid) * 8;
        f32x4 x0 = *(const f32x4*)(X + i);
        f32x4 x1 = *(const f32x4*)(X + i + 4);
        s16x8 r;
        r[0] = (short)f2bf(x0.x); r[1] = (short)f2bf(x0.y);
        r[2] = (short)f2bf(x0.z); r[3] = (short)f2bf(x0.w);
        r[4] = (short)f2bf(x1.x); r[5] = (short)f2bf(x1.y);
        r[6] = (short)f2bf(x1.z); r[7] = (short)f2bf(x1.w);
        *(s16x8*)(Xb + i) = r;
    } else if (b < nconvx + nhist) {
        // histogram with fused rank capture
        int i = (b - nconvx) * 256 + tid;
        if (i < e) rank[i] = atomicAdd(&cnt[rows[i]], 1);
    } else {
        // W f32 -> bf16
        int i = (b - nconvx - nhist) * 256 + tid;
        if (i < 256 * 256) Wb[i] = f2bf(W[i]);
    }
}

// ================= K2: gemm_h (+ fused a1/a2 epilogue) | scan1 ==================
// gemm: block = 4 waves, tile 32 nodes x 256 outs; wave w covers outs [w*64,w*64+64).
// a1/a2 computed from f32 accumulators (pre bf16 rounding) + bias: closer to ref,
// kills the separate a_scores kernel's 51 MB Hb re-read.
__global__ __launch_bounds__(256) void k2_gemm_scan(
    const unsigned short* __restrict__ Xb, const unsigned short* __restrict__ Wb,
    const float* __restrict__ bvec, unsigned short* __restrict__ Hb,
    const float* __restrict__ wa1, const float* __restrict__ ba1,
    const float* __restrict__ wa2, const float* __restrict__ ba2,
    float* __restrict__ a1, float* __restrict__ a2,
    const int* __restrict__ cnt, int* __restrict__ off, int* __restrict__ bsum,
    int ngemm, int n) {
    __shared__ float red[2][4][32];   // gemm branch: [a1|a2][wave][node-in-tile]
    __shared__ int slds[256];         // scan branch
    const int tid = threadIdx.x;

    if ((int)blockIdx.x < ngemm) {
        const int lane = tid & 63;
        const int wave = tid >> 6;
        const int l15 = lane & 15, quad = lane >> 4;
        const int nbase = blockIdx.x * 32;
        const int obase = wave * 64;

        f32x4 acc[2][4] = {};
#pragma unroll
        for (int k = 0; k < 256; k += 32) {
            s16x8 afr[2];
#pragma unroll
            for (int mt = 0; mt < 2; ++mt)
                afr[mt] = *(const s16x8*)(Xb + (size_t)(nbase + mt * 16 + l15) * 256 + k + quad * 8);
#pragma unroll
            for (int t = 0; t < 4; ++t) {
                s16x8 bfr = *(const s16x8*)(Wb + (size_t)(obase + t * 16 + l15) * 256 + k + quad * 8);
                acc[0][t] = __builtin_amdgcn_mfma_f32_16x16x32_bf16(afr[0], bfr, acc[0][t], 0, 0, 0);
                acc[1][t] = __builtin_amdgcn_mfma_f32_16x16x32_bf16(afr[1], bfr, acc[1][t], 0, 0, 0);
            }
        }
        float bvv[4], w1v[4], w2v[4];
#pragma unroll
        for (int t = 0; t < 4; ++t) {
            int o = obase + t * 16 + l15;
            bvv[t] = bvec[o];
            w1v[t] = wa1[o];
            w2v[t] = wa2[o];
        }
#pragma unroll
        for (int mt = 0; mt < 2; ++mt) {
#pragma unroll
            for (int r = 0; r < 4; ++r) {
                const int node = nbase + mt * 16 + quad * 4 + r;
                float h0 = acc[mt][0][r] + bvv[0];
                float h1 = acc[mt][1][r] + bvv[1];
                float h2 = acc[mt][2][r] + bvv[2];
                float h3 = acc[mt][3][r] + bvv[3];
                unsigned short* hp = Hb + (size_t)node * 256 + obase + l15;
                hp[0]  = f2bf(h0);
                hp[16] = f2bf(h1);
                hp[32] = f2bf(h2);
                hp[48] = f2bf(h3);
                float p1 = h0 * w1v[0] + h1 * w1v[1] + h2 * w1v[2] + h3 * w1v[3];
                float p2 = h0 * w2v[0] + h1 * w2v[1] + h2 * w2v[2] + h3 * w2v[3];
#pragma unroll
                for (int m = 1; m < 16; m <<= 1) {  // reduce over l15 group
                    p1 += __shfl_xor(p1, m);
                    p2 += __shfl_xor(p2, m);
                }
                if (l15 == 0) {
                    red[0][wave][mt * 16 + quad * 4 + r] = p1;
                    red[1][wave][mt * 16 + quad * 4 + r] = p2;
                }
            }
        }
        __syncthreads();
        if (tid < 32) {
            a1[nbase + tid] = red[0][0][tid] + red[0][1][tid] + red[0][2][tid] + red[0][3][tid] + ba1[0];
        } else if (tid < 64) {
            int t2 = tid - 32;
            a2[nbase + t2] = red[1][0][t2] + red[1][1][t2] + red[1][2][t2] + red[1][3][t2] + ba2[0];
        }
    } else {
        // -------- scan1: per-2048-chunk inclusive scan of cnt into off[1..] --------
        const int blk = blockIdx.x - ngemm;
        const int base = blk * 2048 + tid * 8;
        int v[8];
        int run = 0;
#pragma unroll
        for (int j = 0; j < 8; ++j) {
            int idx = base + j;
            int x = (idx < n) ? cnt[idx] : 0;
            run += x;
            v[j] = run;
        }
        slds[tid] = run;
        __syncthreads();
#pragma unroll
        for (int ofs = 1; ofs < 256; ofs <<= 1) {
            int t = (tid >= ofs) ? slds[tid - ofs] : 0;
            __syncthreads();
            slds[tid] += t;
            __syncthreads();
        }
        int pre = slds[tid] - run;
#pragma unroll
        for (int j = 0; j < 8; ++j) {
            int idx = base + j;
            if (idx < n) off[1 + idx] = v[j] + pre;
        }
        if (tid == 255) bsum[blk] = slds[255];
    }
}

// ================= scan2: wave-parallel exclusive scan of block sums ============
__global__ void scan2(int* __restrict__ bsum, int* __restrict__ off, int nb) {
    const int lane = threadIdx.x & 63;
    int run = 0;
    for (int base = 0; base < nb; base += 64) {
        int i = base + lane;
        int v = (i < nb) ? bsum[i] : 0;
        int s = v;
#pragma unroll
        for (int o = 1; o < 64; o <<= 1) {
            int t = __shfl_up(s, o);
            if (lane >= o) s += t;
        }
        if (i < nb) bsum[i] = s - v + run;   // exclusive + carry
        run += __shfl(s, 63);
    }
    if (lane == 0) off[0] = 0;
}

// ================= scatter with on-the-fly final offsets (scan3 deleted) ========
// final_off[j] = off[j] + bsum[(j-1)>>11]  (j>=1), 0 for j==0; bsum is 49 ints (L1).
__global__ void scatter_k(const int* __restrict__ rows, const int* __restrict__ colsIn,
                          const int* __restrict__ rank, const int* __restrict__ off,
                          const int* __restrict__ bsum, int* __restrict__ colsOut, int e) {
    int i = blockIdx.x * 256 + threadIdx.x;
    if (i < e) {
        int r = rows[i];
        int base = (r == 0) ? 0 : (off[r] + bsum[(r - 1) >> 11]);
        colsOut[base + rank[i]] = colsIn[i];
    }
}

// ================= softmax + weighted aggregation ===============================
// block = 256 = 4 waves, one node per wave. Wave split into halves: each half
// (32 lanes x dwordx4 = 512 B) reads one full H row -> 2 edges per load instr.
// Lane q&31 owns dims [q*8, q*8+8); halves combined at the end via shfl_xor(32).
// LDS strictly per-wave -> no __syncthreads (wave-lockstep orders write->read).
__global__ __launch_bounds__(256) void aggregate(
    const int* __restrict__ off, const int* __restrict__ bsum,
    const int* __restrict__ cols,
    const float* __restrict__ a1, const float* __restrict__ a2,
    const unsigned short* __restrict__ Hb, float* __restrict__ out) {
    __shared__ float s_ev[4][MAXDEG + 1];
    __shared__ int s_col[4][MAXDEG + 1];
    const int lane = threadIdx.x & 63;
    const int wave = threadIdx.x >> 6;
    const int q = lane & 31;
    const int half = lane >> 5;
    const int node = blockIdx.x * 4 + wave;
    const int o0 = (node == 0) ? 0 : (off[node] + bsum[(node - 1) >> 11]);
    const int o1 = off[node + 1] + bsum[node >> 11];
    const int deg = o1 - o0;
    const float a1n = a1[node];

    // pass 1: scores -> exp (unnormalized), LDS stash, denominator
    float s = 0.0f;
    for (int i = lane; i < deg; i += 64) {
        int c = cols[o0 + i];
        float v = a1n + a2[c];
        v = (v > 0.0f) ? v : 0.01f * v;
        float ev = __expf(v);
        if (i < MAXDEG) {
            s_ev[wave][i] = ev;
            s_col[wave][i] = c;
        }
        s += ev;
    }
#pragma unroll
    for (int o = 32; o; o >>= 1) s += __shfl_xor(s, o);
    float inv = (s > 0.0f) ? 1.0f / s : 0.0f;

    const int nfast = (deg < MAXDEG) ? deg : MAXDEG;
    if (lane == 0) {  // pad one slot so pair loops can overrun odd deg by 1
        s_ev[wave][nfast] = 0.0f;
        s_col[wave][nfast] = 0;
    }

    // pass 2: acc[j] over dims [q*8, q*8+8); this half processes edges i+half
    float acc[8] = {0, 0, 0, 0, 0, 0, 0, 0};
    const unsigned short* __restrict__ hb_q = Hb + q * 8;
    const int E2 = (nfast + 1) & ~1;
    int i = 0;
    for (; i + 8 <= E2; i += 8) {   // 4 pairs = 8 edges, 4 dwordx4 loads in flight
        float w0 = s_ev[wave][i + half];     int c0 = s_col[wave][i + half];
        float w1 = s_ev[wave][i + 2 + half]; int c1 = s_col[wave][i + 2 + half];
        float w2 = s_ev[wave][i + 4 + half]; int c2 = s_col[wave][i + 4 + half];
        float w3 = s_ev[wave][i + 6 + half]; int c3 = s_col[wave][i + 6 + half];
        uint4 h0 = *(const uint4*)(hb_q + (size_t)c0 * 256);
        uint4 h1 = *(const uint4*)(hb_q + (size_t)c1 * 256);
        uint4 h2 = *(const uint4*)(hb_q + (size_t)c2 * 256);
        uint4 h3 = *(const uint4*)(hb_q + (size_t)c3 * 256);
        acc[0] += w0 * bf_lo(h0.x); acc[1] += w0 * bf_hi(h0.x);
        acc[2] += w0 * bf_lo(h0.y); acc[3] += w0 * bf_hi(h0.y);
        acc[4] += w0 * bf_lo(h0.z); acc[5] += w0 * bf_hi(h0.z);
        acc[6] += w0 * bf_lo(h0.w); acc[7] += w0 * bf_hi(h0.w);
        acc[0] += w1 * bf_lo(h1.x); acc[1] += w1 * bf_hi(h1.x);
        acc[2] += w1 * bf_lo(h1.y); acc[3] += w1 * bf_hi(h1.y);
        acc[4] += w1 * bf_lo(h1.z); acc[5] += w1 * bf_hi(h1.z);
        acc[6] += w1 * bf_lo(h1.w); acc[7] += w1 * bf_hi(h1.w);
        acc[0] += w2 * bf_lo(h2.x); acc[1] += w2 * bf_hi(h2.x);
        acc[2] += w2 * bf_lo(h2.y); acc[3] += w2 * bf_hi(h2.y);
        acc[4] += w2 * bf_lo(h2.z); acc[5] += w2 * bf_hi(h2.z);
        acc[6] += w2 * bf_lo(h2.w); acc[7] += w2 * bf_hi(h2.w);
        acc[0] += w3 * bf_lo(h3.x); acc[1] += w3 * bf_hi(h3.x);
        acc[2] += w3 * bf_lo(h3.y); acc[3] += w3 * bf_hi(h3.y);
        acc[4] += w3 * bf_lo(h3.z); acc[5] += w3 * bf_hi(h3.z);
        acc[6] += w3 * bf_lo(h3.w); acc[7] += w3 * bf_hi(h3.w);
    }
    for (; i < E2; i += 2) {        // pair tail
        float w = s_ev[wave][i + half];
        int c = s_col[wave][i + half];
        uint4 hv = *(const uint4*)(hb_q + (size_t)c * 256);
        acc[0] += w * bf_lo(hv.x); acc[1] += w * bf_hi(hv.x);
        acc[2] += w * bf_lo(hv.y); acc[3] += w * bf_hi(hv.y);
        acc[4] += w * bf_lo(hv.z); acc[5] += w * bf_hi(hv.z);
        acc[6] += w * bf_lo(hv.w); acc[7] += w * bf_hi(hv.w);
    }
    for (int j = MAXDEG; j < deg; j += 2) {  // rare overflow path
        int jj = j + half;
        float w = 0.0f;
        int c = 0;
        if (jj < deg) {
            c = cols[o0 + jj];
            float v = a1n + a2[c];
            v = (v > 0.0f) ? v : 0.01f * v;
            w = __expf(v);
        }
        uint4 hv = *(const uint4*)(hb_q + (size_t)c * 256);
        acc[0] += w * bf_lo(hv.x); acc[1] += w * bf_hi(hv.x);
        acc[2] += w * bf_lo(hv.y); acc[3] += w * bf_hi(hv.y);
        acc[4] += w * bf_lo(hv.z); acc[5] += w * bf_hi(hv.z);
        acc[6] += w * bf_lo(hv.w); acc[7] += w * bf_hi(hv.w);
    }
#pragma unroll
    for (int j = 0; j < 8; ++j) acc[j] = (acc[j] + __shfl_xor(acc[j], 32)) * inv;
    if (half == 0) {
        float* op = out + (size_t)node * 256 + q * 8;
        f32x4 lo = {acc[0], acc[1], acc[2], acc[3]};
        f32x4 hi = {acc[4], acc[5], acc[6], acc[7]};
        *(f32x4*)op = lo;
        *(f32x4*)(op + 4) = hi;
    }
}

extern "C" void kernel_launch(void* const* d_in, const int* in_sizes, int n_in,
                              void* d_out, int out_size, void* d_ws, size_t ws_size,
                              hipStream_t stream) {
    const float* X   = (const float*)d_in[0];
    const int*   idx = (const int*)d_in[1];
    const float* W   = (const float*)d_in[2];
    const float* b   = (const float*)d_in[3];
    const float* wa1 = (const float*)d_in[4];
    const float* ba1 = (const float*)d_in[5];
    const float* wa2 = (const float*)d_in[6];
    const float* ba2 = (const float*)d_in[7];
    float* out = (float*)d_out;

    const int n = in_sizes[0] / 256;  // 100000
    const int e = in_sizes[1] / 2;    // 3200000

    char* p = (char*)d_ws;
    auto alloc = [&](size_t bytes) -> char* {
        char* r = p;
        p += (bytes + 255) & ~(size_t)255;
        return r;
    };
    unsigned short* Hb = (unsigned short*)alloc((size_t)n * 256 * 2);
    unsigned short* Xb = (unsigned short*)alloc((size_t)n * 256 * 2);
    unsigned short* Wb = (unsigned short*)alloc(256 * 256 * 2);
    float* a1  = (float*)alloc((size_t)n * 4);
    float* a2  = (float*)alloc((size_t)n * 4);
    int* cnt   = (int*)alloc((size_t)n * 4);
    int* off   = (int*)alloc((size_t)(n + 1) * 4);
    int* bsum  = (int*)alloc(256 * 4);
    int* rank  = (int*)alloc((size_t)e * 4);
    int* colS  = (int*)alloc((size_t)e * 4);

    const int* rows   = idx;
    const int* colsIn = idx + e;

    hipMemsetAsync(cnt, 0, (size_t)n * 4, stream);

    const int nconvx = (n * 256) / (256 * 8);   // 12500
    const int nhist  = (e + 255) / 256;         // 12500
    const int nconvw = 256;
    k1_prep<<<nconvx + nhist + nconvw, 256, 0, stream>>>(X, Xb, W, Wb, rows, cnt, rank,
                                                          nconvx, nhist, e);
    const int ngemm = n / 32;                   // 3125
    const int nscan = (n + 2047) / 2048;        // 49
    k2_gemm_scan<<<ngemm + nscan, 256, 0, stream>>>(Xb, Wb, b, Hb, wa1, ba1, wa2, ba2,
                                                     a1, a2, cnt, off, bsum, ngemm, n);
    scan2<<<1, 64, 0, stream>>>(bsum, off, nscan);
    scatter_k<<<(e + 255) / 256, 256, 0, stream>>>(rows, colsIn, rank, off, bsum, colS, e);
    aggregate<<<n / 4, 256, 0, stream>>>(off, bsum, colS, a1, a2, Hb, out);
}